// Round 1
// 278.167 us; speedup vs baseline: 1.0669x; 1.0669x over previous
//
#include <hip/hip_runtime.h>
#include <stdint.h>
#include <math.h>

#define DEVI __device__ __forceinline__

typedef __attribute__((ext_vector_type(8))) short bf16x8;
typedef __attribute__((ext_vector_type(4))) float f32x4;

DEVI unsigned short f2bf(float f) {
  union { float f; unsigned u; } v; v.f = f;
  unsigned u = v.u;
  u += 0x7fffu + ((u >> 16) & 1u);   // round-to-nearest-even
  return (unsigned short)(u >> 16);
}

// pack two f32 -> one dword of 2x bf16 (lo = a, hi = b), RNE; no builtin on gfx950
DEVI unsigned cvt_pk_bf16(float a, float b) {
  unsigned r;
  asm("v_cvt_pk_bf16_f32 %0, %1, %2" : "=v"(r) : "v"(a), "v"(b));
  return r;
}

DEVI f32x4 mfma16(bf16x8 a, bf16x8 b, f32x4 c) {
  return __builtin_amdgcn_mfma_f32_16x16x32_bf16(a, b, c, 0, 0, 0);
}

// async global->LDS, 16 B per lane; LDS dest = wave-uniform base + lane*16
DEVI void gld16(const unsigned short* g, unsigned short* l) {
  __builtin_amdgcn_global_load_lds(
      (const __attribute__((address_space(1))) unsigned int*)(uintptr_t)g,
      (__attribute__((address_space(3))) unsigned int*)(unsigned int)(uintptr_t)l,
      16, 0, 0);
}

// ---------------- fp32 -> bf16 convert ----------------
__global__ __launch_bounds__(256) void cvt_kernel(const float* __restrict__ in,
                                                  unsigned short* __restrict__ out, int n) {
  int i = (blockIdx.x * 256 + threadIdx.x) * 4;
  if (i < n) {
    float4 v = *(const float4*)(in + i);
    unsigned lo = f2bf(v.x) | ((unsigned)f2bf(v.y) << 16);
    unsigned hi = f2bf(v.z) | ((unsigned)f2bf(v.w) << 16);
    uint2 o; o.x = lo; o.y = hi;
    *(uint2*)(out + i) = o;
  }
}

// ---------------- GEMM: C[M,N] = A[M,K] * Bw[N,K]^T + bias ----------------
template <int MODE>
__global__ __launch_bounds__(256) void gemm_bt(
    const unsigned short* __restrict__ A, const unsigned short* __restrict__ Bw,
    const float* __restrict__ bias, float* __restrict__ Cf,
    unsigned short* __restrict__ Qo, unsigned short* __restrict__ Ko,
    unsigned short* __restrict__ Vo, int M, int N, int K) {
  __shared__ unsigned short As[128 * 64];
  __shared__ unsigned short Bs[128 * 64];
  const int tid = threadIdx.x;
  const int lane = tid & 63;
  const int w = tid >> 6;
  const int wm = w & 1, wn = w >> 1;
  const int lr = lane & 15, lq = lane >> 4;
  const int m0 = blockIdx.y * 128;
  const int n0 = blockIdx.x * 128;
  const int l8r = lane >> 3;        // 0..7
  const int l8c = (lane & 7) << 3;  // 0..56

  f32x4 acc[4][4] = {};

  for (int kt = 0; kt < K; kt += 64) {
    __syncthreads();
#pragma unroll
    for (int i = 0; i < 4; ++i) {
      int c = w * 4 + i;            // 0..15, 8 rows per call
      int row = c * 8 + l8r;
      gld16(A + (size_t)(m0 + row) * K + kt + l8c, &As[c * 8 * 64]);
      gld16(Bw + (size_t)(n0 + row) * K + kt + l8c, &Bs[c * 8 * 64]);
    }
    __syncthreads();
#pragma unroll
    for (int kk = 0; kk < 64; kk += 32) {
      bf16x8 af[4], bfr[4];
#pragma unroll
      for (int mt = 0; mt < 4; ++mt)
        af[mt] = *(const bf16x8*)(&As[(wm * 64 + mt * 16 + lr) * 64 + kk + lq * 8]);
#pragma unroll
      for (int nt = 0; nt < 4; ++nt)
        bfr[nt] = *(const bf16x8*)(&Bs[(wn * 64 + nt * 16 + lr) * 64 + kk + lq * 8]);
#pragma unroll
      for (int mt = 0; mt < 4; ++mt)
#pragma unroll
        for (int nt = 0; nt < 4; ++nt)
          acc[mt][nt] = mfma16(af[mt], bfr[nt], acc[mt][nt]);
    }
  }

#pragma unroll
  for (int mt = 0; mt < 4; ++mt) {
#pragma unroll
    for (int nt = 0; nt < 4; ++nt) {
      int n_g = n0 + wn * 64 + nt * 16 + lr;
      float bv = bias[n_g];
#pragma unroll
      for (int r = 0; r < 4; ++r) {
        int m_g = m0 + wm * 64 + mt * 16 + lq * 4 + r;
        float v = acc[mt][nt][r] + bv;
        if (MODE == 1) {
          Cf[(size_t)m_g * N + n_g] = v;
        } else {
          int which = n_g >> 10;               // 0:Q 1:K 2:V
          int rem = n_g & 1023;
          int h = rem >> 6, d = rem & 63;
          int b = m_g >> 11, t = m_g & 2047;
          size_t idx = (((size_t)(b * 16 + h) * 2048) + t) * 64 + d;
          unsigned short* p = (which == 0) ? Qo : ((which == 1) ? Ko : Vo);
          p[idx] = f2bf(v);
        }
      }
    }
  }
}

// ------- flash attention (causal), S^T formulation, 128-row Q-tiles -------
// Block: 8 waves x 16 q-rows = 128 q-rows; processes paired q-tiles
// (pair, 15-pair) -> uniform 34 KV-iterations per block. Grid 512 blocks,
// 512 threads -> 16 waves/CU (4/SIMD), double current occupancy.
// K/V double-buffered in LDS -> ONE barrier per KV tile:
//   compute(buf) ; stage(buf^1) ; barrier
// (readers touch buf only, the stage touches buf^1 only; at the phase seam
//  the last tile is always buf1 while the next prologue stages buf0).
__global__ __launch_bounds__(512, 4) void attn_kernel(
    const unsigned short* __restrict__ Q, const unsigned short* __restrict__ K,
    const unsigned short* __restrict__ V, unsigned short* __restrict__ Y) {
  constexpr int T = 2048, HD = 64, H = 16;
  __shared__ unsigned short Kt[2][64 * 72];   // K rows [kv][d], pad 8
  __shared__ unsigned short Vt[2][64 * 72];   // V^T    [d][kv], pad 8
  __shared__ unsigned short Pt[8][16 * 72];   // per-wave P, [q][kv]

  const int tid = threadIdx.x;
  const int lane = tid & 63;
  const int w = tid >> 6;                     // 0..7
  const int lr = lane & 15, lq = lane >> 4;
  const int pair = blockIdx.x;                // 0..7
  const int h = blockIdx.y;
  const int b = blockIdx.z;
  const size_t bh = (size_t)(b * H + h) * T * HD;
  const float SC = 0.125f * 1.44269504089f;   // 1/sqrt(64) * log2(e)

  // staging coords: exactly one float4 per thread for K and for V
  const int krow = tid >> 3, kcb = (tid & 7) << 3;  // K: 64 rows x 64 cols
  const int vrow = lane, vc = w << 3;               // V: transpose write

  float4 kr, vr;
  auto load_tile = [&](int jt) {
    const int c0 = jt * 64;
    kr = *(const float4*)(K + bh + (size_t)(c0 + krow) * HD + kcb);
    vr = *(const float4*)(V + bh + (size_t)(c0 + vrow) * HD + vc);
  };
  auto stage = [&](int buf) {
    *(float4*)(&Kt[buf][krow * 72 + kcb]) = kr;
    const unsigned short* vp = (const unsigned short*)&vr;
#pragma unroll
    for (int j = 0; j < 8; ++j) Vt[buf][(vc + j) * 72 + vrow] = vp[j];
  };

  load_tile(0);

  for (int phase = 0; phase < 2; ++phase) {
    const int qt = phase ? (15 - pair) : pair;
    const int q0 = qt * 128;
    const int nkv = 2 * qt + 2;
    const int qmin = q0 + w * 16;        // wave's min q-row
    const int qmax = qmin + 15;

    // Q B-fragments (q = lr within the wave's 16-row set)
    bf16x8 qf[2];
#pragma unroll
    for (int kb = 0; kb < 2; ++kb)
      qf[kb] = *(const bf16x8*)(Q + bh + (size_t)(qmin + lr) * HD + kb * 32 + lq * 8);

    f32x4 o[4] = {};
    float mi = -INFINITY, li = 0.f;

    // prologue: regs hold this phase's tile 0
    stage(0);
    load_tile(1);
    __syncthreads();

    for (int jt = 0; jt < nkv; ++jt) {
      const int c0 = jt * 64;
      const int buf = jt & 1;

      if (c0 <= qmax) {                  // wave-uniform: else tile fully masked
        // S^T = K Q^T : rows kv, cols q
        f32x4 s[4];
#pragma unroll
        for (int nt = 0; nt < 4; ++nt) {
          bf16x8 kf0 = *(const bf16x8*)(&Kt[buf][(nt * 16 + lr) * 72 + lq * 8]);
          bf16x8 kf1 = *(const bf16x8*)(&Kt[buf][(nt * 16 + lr) * 72 + 32 + lq * 8]);
          f32x4 z = {};
          z = mfma16(kf0, qf[0], z);
          s[nt] = mfma16(kf1, qf[1], z);
        }
        // scale (+ causal mask only near the diagonal; wave-uniform branch)
        if (c0 + 63 > qmin) {
          int qg = qmin + lr;
#pragma unroll
          for (int nt = 0; nt < 4; ++nt)
#pragma unroll
            for (int r = 0; r < 4; ++r) {
              int kvg = c0 + nt * 16 + lq * 4 + r;
              s[nt][r] = (kvg > qg) ? -INFINITY : s[nt][r] * SC;
            }
        } else {
#pragma unroll
          for (int nt = 0; nt < 4; ++nt)
#pragma unroll
            for (int r = 0; r < 4; ++r) s[nt][r] *= SC;
        }
        // online softmax, one q-row per lane (reduce across lq groups)
        float mx = -INFINITY;
#pragma unroll
        for (int nt = 0; nt < 4; ++nt)
          mx = fmaxf(mx, fmaxf(fmaxf(s[nt][0], s[nt][1]),
                               fmaxf(s[nt][2], s[nt][3])));
        mx = fmaxf(mx, __shfl_xor(mx, 16));
        mx = fmaxf(mx, __shfl_xor(mx, 32));
        float mnew = fmaxf(mi, mx);
        float alpha = __builtin_amdgcn_exp2f(mi - mnew);
        mi = mnew;
        float rs = 0.f;
#pragma unroll
        for (int nt = 0; nt < 4; ++nt) {
          float p0 = __builtin_amdgcn_exp2f(s[nt][0] - mnew);
          float p1 = __builtin_amdgcn_exp2f(s[nt][1] - mnew);
          float p2 = __builtin_amdgcn_exp2f(s[nt][2] - mnew);
          float p3 = __builtin_amdgcn_exp2f(s[nt][3] - mnew);
          rs += (p0 + p1) + (p2 + p3);
          uint2 pk;
          pk.x = cvt_pk_bf16(p0, p1);
          pk.y = cvt_pk_bf16(p2, p3);
          *(uint2*)(&Pt[w][lr * 72 + nt * 16 + lq * 4]) = pk;
        }
        rs += __shfl_xor(rs, 16);
        rs += __shfl_xor(rs, 32);
        li = li * alpha + rs;
#pragma unroll
        for (int nt = 0; nt < 4; ++nt)
#pragma unroll
          for (int r = 0; r < 4; ++r) o[nt][r] *= alpha;
        // O^T += V^T P^T  (A = V^T frag, B = P^T frag)
        bf16x8 pf[2];
#pragma unroll
        for (int kb = 0; kb < 2; ++kb)
          pf[kb] = *(const bf16x8*)(&Pt[w][lr * 72 + kb * 32 + lq * 8]);
#pragma unroll
        for (int nt = 0; nt < 4; ++nt) {
          bf16x8 vf0 = *(const bf16x8*)(&Vt[buf][(nt * 16 + lr) * 72 + lq * 8]);
          bf16x8 vf1 = *(const bf16x8*)(&Vt[buf][(nt * 16 + lr) * 72 + 32 + lq * 8]);
          o[nt] = mfma16(vf0, pf[0], o[nt]);
          o[nt] = mfma16(vf1, pf[1], o[nt]);
        }
      }

      // stage next tile into the other buffer; ONE barrier per tile
      if (jt + 1 < nkv) {
        stage(buf ^ 1);
        if (jt + 2 < nkv) load_tile(jt + 2);
        else if (phase == 0) load_tile(0);   // prefetch phase-1's tile 0
        __syncthreads();
      }
    }

    // epilogue: Y[b, t=q, h*64 + d]; lane holds q=lr, d=nt*16+lq*4+r
    {
      float inv = 1.f / li;
      int t_g = qmin + lr;
#pragma unroll
      for (int nt = 0; nt < 4; ++nt) {
        uint2 yv;
        yv.x = cvt_pk_bf16(o[nt][0] * inv, o[nt][1] * inv);
        yv.y = cvt_pk_bf16(o[nt][2] * inv, o[nt][3] * inv);
        *(uint2*)(Y + ((size_t)(b * T + t_g)) * 1024 + h * 64 + nt * 16 + lq * 4) = yv;
      }
    }
  }
}

// ---------------- launch ----------------
extern "C" void kernel_launch(void* const* d_in, const int* in_sizes, int n_in,
                              void* d_out, int out_size, void* d_ws, size_t ws_size,
                              hipStream_t stream) {
  const float* x = (const float*)d_in[0];       // [4,2048,1024]
  const float* qkv_w = (const float*)d_in[1];   // [3072,1024]
  const float* qkv_b = (const float*)d_in[2];   // [3072]
  const float* proj_w = (const float*)d_in[3];  // [1024,1024]
  const float* proj_b = (const float*)d_in[4];  // [1024]
  float* out = (float*)d_out;                   // [4,2048,1024] fp32

  unsigned short* ws = (unsigned short*)d_ws;
  unsigned short* xb = ws;                     // 8388608
  unsigned short* wqkv = xb + 8388608;         // 3145728
  unsigned short* wproj = wqkv + 3145728;      // 1048576
  unsigned short* Qb = wproj + 1048576;        // 8388608 [B,H,T,hd]
  unsigned short* Kb = Qb + 8388608;           // 8388608
  unsigned short* Vb = Kb + 8388608;           // 8388608
  unsigned short* Yb = Vb + 8388608;           // 8388608 [B*T, C]

  cvt_kernel<<<8388608 / 1024, 256, 0, stream>>>(x, xb, 8388608);
  cvt_kernel<<<3145728 / 1024, 256, 0, stream>>>(qkv_w, wqkv, 3145728);
  cvt_kernel<<<1048576 / 1024, 256, 0, stream>>>(proj_w, wproj, 1048576);

  gemm_bt<0><<<dim3(24, 64), 256, 0, stream>>>(xb, wqkv, qkv_b, nullptr, Qb, Kb, Vb,
                                               8192, 3072, 1024);
  attn_kernel<<<dim3(8, 16, 4), 512, 0, stream>>>(Qb, Kb, Vb, Yb);
  gemm_bt<1><<<dim3(8, 64), 256, 0, stream>>>(Yb, wproj, proj_b, out, nullptr, nullptr,
                                              nullptr, 8192, 1024, 1024);
}

// Round 2
// 261.371 us; speedup vs baseline: 1.1355x; 1.0643x over previous
//
#include <hip/hip_runtime.h>
#include <stdint.h>
#include <math.h>

#define DEVI __device__ __forceinline__

typedef __attribute__((ext_vector_type(8))) short bf16x8;
typedef __attribute__((ext_vector_type(4))) float f32x4;

DEVI unsigned short f2bf(float f) {
  union { float f; unsigned u; } v; v.f = f;
  unsigned u = v.u;
  u += 0x7fffu + ((u >> 16) & 1u);   // round-to-nearest-even
  return (unsigned short)(u >> 16);
}

// pack two f32 -> one dword of 2x bf16 (lo = a, hi = b), RNE; no builtin on gfx950
DEVI unsigned cvt_pk_bf16(float a, float b) {
  unsigned r;
  asm("v_cvt_pk_bf16_f32 %0, %1, %2" : "=v"(r) : "v"(a), "v"(b));
  return r;
}

DEVI f32x4 mfma16(bf16x8 a, bf16x8 b, f32x4 c) {
  return __builtin_amdgcn_mfma_f32_16x16x32_bf16(a, b, c, 0, 0, 0);
}

// async global->LDS, 16 B per lane; LDS dest = wave-uniform base + lane*16
DEVI void gld16(const unsigned short* g, unsigned short* l) {
  __builtin_amdgcn_global_load_lds(
      (const __attribute__((address_space(1))) unsigned int*)(uintptr_t)g,
      (__attribute__((address_space(3))) unsigned int*)(unsigned int)(uintptr_t)l,
      16, 0, 0);
}

#define VMCNT(n) asm volatile("s_waitcnt vmcnt(" #n ")" ::: "memory")
#define BAR()                              \
  do {                                     \
    __builtin_amdgcn_s_barrier();          \
    __builtin_amdgcn_sched_barrier(0);     \
  } while (0)

// ---------------- fp32 -> bf16 convert ----------------
__global__ __launch_bounds__(256) void cvt_kernel(const float* __restrict__ in,
                                                  unsigned short* __restrict__ out, int n) {
  int i = (blockIdx.x * 256 + threadIdx.x) * 4;
  if (i < n) {
    float4 v = *(const float4*)(in + i);
    unsigned lo = f2bf(v.x) | ((unsigned)f2bf(v.y) << 16);
    unsigned hi = f2bf(v.z) | ((unsigned)f2bf(v.w) << 16);
    uint2 o; o.x = lo; o.y = hi;
    *(uint2*)(out + i) = o;
  }
}

// ======== 256x256 deep-pipelined GEMM: C[M,N] = A[M,K]*Bw[N,K]^T + bias ========
// 512 threads = 8 waves (2M x 4N), wave tile 128x64, BK=64, LDS 128 KiB dbuf.
// Staging units per K-tile (each = 2 gld16/thread):
//   A_a = tile rows {0-63, 128-191}   (read by phases 0,1)
//   B_a = B rows {0-31,64-95,128-159,192-223} (phases 0,2)
//   B_b = complement stripes          (phases 1,3)
//   A_b = rows {64-127, 192-255}      (phases 2,3)
// Issue order per tile: A_a, B_a, B_b, A_b -> counted vmcnt(4) gates:
//   end ph0: forces B_b(t) landed; end ph1: forces A_b(t); end ph3: A_a,B_a(t+1).
// LDS read-swizzle (T2) via pre-swizzled global source (linear gld16 dest):
//   logical (r,c8blk) stored at blk' = c8blk ^ (r&7); source col = 8*((l&7)^(l>>3)).
template <int MODE>
__global__ __launch_bounds__(512, 2) void gemm8(
    const unsigned short* __restrict__ A, const unsigned short* __restrict__ Bw,
    const float* __restrict__ bias, float* __restrict__ Cf,
    unsigned short* __restrict__ Qo, unsigned short* __restrict__ Ko,
    unsigned short* __restrict__ Vo, int M, int N, int K, int nbx) {
  extern __shared__ unsigned short lds[];   // [buf][As 16384 | Bs 16384] ushorts
  const int tid = threadIdx.x;
  const int lane = tid & 63;
  const int w = tid >> 6;                   // 0..7
  const int wm = w >> 2, wn = w & 3;
  const int lr = lane & 15, lq = lane >> 4;

  // T1: XCD-aware block swizzle (grid % 8 == 0 for both call sites)
  const int cpx = gridDim.x >> 3;
  const int swz = (blockIdx.x & 7) * cpx + (blockIdx.x >> 3);
  const int bx = swz % nbx, by = swz / nbx;
  const int m0 = by * 256, n0 = bx * 256;

  // staging source coords (swizzle baked into the per-lane global column)
  const int sr = lane >> 3;                       // 0..7 row within chunk
  const int sc = ((lane & 7) ^ sr) << 3;          // swizzled col element
  const unsigned short* pa = A + (size_t)(m0 + sr) * K + sc;
  const unsigned short* pb = Bw + (size_t)(n0 + sr) * K + sc;

  // per-wave chunk ids (chunk = 8 rows = 1 KiB) for each unit
  const int aA0 = w, aA1 = 16 + w;                       // A_a
  const int aB0 = 8 + w, aB1 = 24 + w;                   // A_b
  const int bA0 = (w & 3) + ((w >> 2) << 3), bA1 = bA0 + 16;  // B_a
  const int bB0 = bA0 + 4, bB1 = bA1 + 4;                // B_b

  // fragment-read block swizzle offsets (ushorts); row&7 == lr&7 for all frags
  const int bs0 = (lq ^ (lr & 7)) << 3;
  const int bs1 = ((lq + 4) ^ (lr & 7)) << 3;

  f32x4 acc[8][4] = {};

  auto sA = [&](int buf, int kt, int c) {
    gld16(pa + (size_t)(c << 3) * K + kt, lds + buf * 32768 + (c << 9));
  };
  auto sB = [&](int buf, int kt, int c) {
    gld16(pb + (size_t)(c << 3) * K + kt, lds + buf * 32768 + 16384 + (c << 9));
  };

#define PH(buf, mh, nh)                                                          \
  {                                                                              \
    const unsigned short* As_ = lds + (buf) * 32768;                             \
    const unsigned short* Bs_ = As_ + 16384;                                     \
    bf16x8 a0[4], a1[4], b0[2], b1[2];                                           \
    _Pragma("unroll") for (int i = 0; i < 4; ++i) {                              \
      int ar = wm * 128 + (mh) * 64 + i * 16 + lr;                               \
      a0[i] = *(const bf16x8*)(As_ + ar * 64 + bs0);                             \
      a1[i] = *(const bf16x8*)(As_ + ar * 64 + bs1);                             \
    }                                                                            \
    _Pragma("unroll") for (int j = 0; j < 2; ++j) {                              \
      int br = wn * 64 + (nh) * 32 + j * 16 + lr;                                \
      b0[j] = *(const bf16x8*)(Bs_ + br * 64 + bs0);                             \
      b1[j] = *(const bf16x8*)(Bs_ + br * 64 + bs1);                             \
    }                                                                            \
    __builtin_amdgcn_s_setprio(1);                                               \
    _Pragma("unroll") for (int i = 0; i < 4; ++i)                                \
      _Pragma("unroll") for (int j = 0; j < 2; ++j) {                            \
        acc[(mh) * 4 + i][(nh) * 2 + j] =                                        \
            mfma16(a0[i], b0[j], acc[(mh) * 4 + i][(nh) * 2 + j]);               \
        acc[(mh) * 4 + i][(nh) * 2 + j] =                                        \
            mfma16(a1[i], b1[j], acc[(mh) * 4 + i][(nh) * 2 + j]);               \
      }                                                                          \
    __builtin_amdgcn_s_setprio(0);                                               \
  }

  // prologue: tile 0 into buf0 (unit order A_a, B_a, B_b, A_b)
  sA(0, 0, aA0); sA(0, 0, aA1);
  sB(0, 0, bA0); sB(0, 0, bA1);
  sB(0, 0, bB0); sB(0, 0, bB1);
  sA(0, 0, aB0); sA(0, 0, aB1);
  VMCNT(4);      // A_a(0), B_a(0) landed
  BAR();

  const int NT = K >> 6;
  for (int t = 0; t < NT - 1; ++t) {
    const int buf = t & 1, nb = buf ^ 1;
    const int kt = (t + 1) << 6;
    // phase 0: quadrant (mh=0,nh=0); stage A_a(t+1)
    sA(nb, kt, aA0); sA(nb, kt, aA1);
    PH(buf, 0, 0);
    VMCNT(4); BAR();                 // B_b(t) landed for all waves
    // phase 1: (0,1); stage B_a(t+1)
    sB(nb, kt, bA0); sB(nb, kt, bA1);
    PH(buf, 0, 1);
    VMCNT(4); BAR();                 // A_b(t) landed for all waves
    // phase 2: (1,0); stage B_b(t+1)   (no gate needed before phase 3)
    sB(nb, kt, bB0); sB(nb, kt, bB1);
    PH(buf, 1, 0);
    // phase 3: (1,1); stage A_b(t+1)
    sA(nb, kt, aB0); sA(nb, kt, aB1);
    PH(buf, 1, 1);
    VMCNT(4); BAR();                 // A_a(t+1), B_a(t+1) landed
  }
  { // peeled last tile (no staging; tighter gates, barriers globalize them)
    const int buf = (NT - 1) & 1;
    PH(buf, 0, 0);
    VMCNT(2); BAR();                 // B_b(last) landed
    PH(buf, 0, 1);
    VMCNT(0); BAR();                 // A_b(last) landed
    PH(buf, 1, 0);
    PH(buf, 1, 1);
  }
#undef PH

  // epilogue (same verified mapping; wave tile 128x64)
#pragma unroll
  for (int mt = 0; mt < 8; ++mt) {
#pragma unroll
    for (int nt = 0; nt < 4; ++nt) {
      int n_g = n0 + wn * 64 + nt * 16 + lr;
      float bv = bias[n_g];
#pragma unroll
      for (int r = 0; r < 4; ++r) {
        int m_g = m0 + wm * 128 + mt * 16 + lq * 4 + r;
        float v = acc[mt][nt][r] + bv;
        if (MODE == 1) {
          Cf[(size_t)m_g * N + n_g] = v;
        } else {
          int which = n_g >> 10;               // 0:Q 1:K 2:V
          int rem = n_g & 1023;
          int h = rem >> 6, d = rem & 63;
          int b = m_g >> 11, tt = m_g & 2047;
          size_t idx = (((size_t)(b * 16 + h) * 2048) + tt) * 64 + d;
          unsigned short* p = (which == 0) ? Qo : ((which == 1) ? Ko : Vo);
          p[idx] = f2bf(v);
        }
      }
    }
  }
}

// ------- flash attention (causal), S^T formulation, 128-row Q-tiles -------
// 8 waves x 16 q-rows; paired q-tiles (pair, 15-pair); dbuf K/V, one barrier/tile.
__global__ __launch_bounds__(512, 4) void attn_kernel(
    const unsigned short* __restrict__ Q, const unsigned short* __restrict__ K,
    const unsigned short* __restrict__ V, unsigned short* __restrict__ Y) {
  constexpr int T = 2048, HD = 64, H = 16;
  __shared__ unsigned short Kt[2][64 * 72];   // K rows [kv][d], pad 8
  __shared__ unsigned short Vt[2][64 * 72];   // V^T    [d][kv], pad 8
  __shared__ unsigned short Pt[8][16 * 72];   // per-wave P, [q][kv]

  const int tid = threadIdx.x;
  const int lane = tid & 63;
  const int w = tid >> 6;                     // 0..7
  const int lr = lane & 15, lq = lane >> 4;
  const int pair = blockIdx.x;                // 0..7
  const int h = blockIdx.y;
  const int b = blockIdx.z;
  const size_t bh = (size_t)(b * H + h) * T * HD;
  const float SC = 0.125f * 1.44269504089f;   // 1/sqrt(64) * log2(e)

  const int krow = tid >> 3, kcb = (tid & 7) << 3;  // K: 64 rows x 64 cols
  const int vrow = lane, vc = w << 3;               // V: transpose write

  float4 kr, vr;
  auto load_tile = [&](int jt) {
    const int c0 = jt * 64;
    kr = *(const float4*)(K + bh + (size_t)(c0 + krow) * HD + kcb);
    vr = *(const float4*)(V + bh + (size_t)(c0 + vrow) * HD + vc);
  };
  auto stage = [&](int buf) {
    *(float4*)(&Kt[buf][krow * 72 + kcb]) = kr;
    const unsigned short* vp = (const unsigned short*)&vr;
#pragma unroll
    for (int j = 0; j < 8; ++j) Vt[buf][(vc + j) * 72 + vrow] = vp[j];
  };

  load_tile(0);

  for (int phase = 0; phase < 2; ++phase) {
    const int qt = phase ? (15 - pair) : pair;
    const int q0 = qt * 128;
    const int nkv = 2 * qt + 2;
    const int qmin = q0 + w * 16;
    const int qmax = qmin + 15;

    bf16x8 qf[2];
#pragma unroll
    for (int kb = 0; kb < 2; ++kb)
      qf[kb] = *(const bf16x8*)(Q + bh + (size_t)(qmin + lr) * HD + kb * 32 + lq * 8);

    f32x4 o[4] = {};
    float mi = -INFINITY, li = 0.f;

    stage(0);
    load_tile(1);
    __syncthreads();

    for (int jt = 0; jt < nkv; ++jt) {
      const int c0 = jt * 64;
      const int buf = jt & 1;

      if (c0 <= qmax) {
        f32x4 s[4];
#pragma unroll
        for (int nt = 0; nt < 4; ++nt) {
          bf16x8 kf0 = *(const bf16x8*)(&Kt[buf][(nt * 16 + lr) * 72 + lq * 8]);
          bf16x8 kf1 = *(const bf16x8*)(&Kt[buf][(nt * 16 + lr) * 72 + 32 + lq * 8]);
          f32x4 z = {};
          z = mfma16(kf0, qf[0], z);
          s[nt] = mfma16(kf1, qf[1], z);
        }
        if (c0 + 63 > qmin) {
          int qg = qmin + lr;
#pragma unroll
          for (int nt = 0; nt < 4; ++nt)
#pragma unroll
            for (int r = 0; r < 4; ++r) {
              int kvg = c0 + nt * 16 + lq * 4 + r;
              s[nt][r] = (kvg > qg) ? -INFINITY : s[nt][r] * SC;
            }
        } else {
#pragma unroll
          for (int nt = 0; nt < 4; ++nt)
#pragma unroll
            for (int r = 0; r < 4; ++r) s[nt][r] *= SC;
        }
        float mx = -INFINITY;
#pragma unroll
        for (int nt = 0; nt < 4; ++nt)
          mx = fmaxf(mx, fmaxf(fmaxf(s[nt][0], s[nt][1]),
                               fmaxf(s[nt][2], s[nt][3])));
        mx = fmaxf(mx, __shfl_xor(mx, 16));
        mx = fmaxf(mx, __shfl_xor(mx, 32));
        float mnew = fmaxf(mi, mx);
        float alpha = __builtin_amdgcn_exp2f(mi - mnew);
        mi = mnew;
        float rs = 0.f;
#pragma unroll
        for (int nt = 0; nt < 4; ++nt) {
          float p0 = __builtin_amdgcn_exp2f(s[nt][0] - mnew);
          float p1 = __builtin_amdgcn_exp2f(s[nt][1] - mnew);
          float p2 = __builtin_amdgcn_exp2f(s[nt][2] - mnew);
          float p3 = __builtin_amdgcn_exp2f(s[nt][3] - mnew);
          rs += (p0 + p1) + (p2 + p3);
          uint2 pk;
          pk.x = cvt_pk_bf16(p0, p1);
          pk.y = cvt_pk_bf16(p2, p3);
          *(uint2*)(&Pt[w][lr * 72 + nt * 16 + lq * 4]) = pk;
        }
        rs += __shfl_xor(rs, 16);
        rs += __shfl_xor(rs, 32);
        li = li * alpha + rs;
#pragma unroll
        for (int nt = 0; nt < 4; ++nt)
#pragma unroll
          for (int r = 0; r < 4; ++r) o[nt][r] *= alpha;
        bf16x8 pf[2];
#pragma unroll
        for (int kb = 0; kb < 2; ++kb)
          pf[kb] = *(const bf16x8*)(&Pt[w][lr * 72 + kb * 32 + lq * 8]);
#pragma unroll
        for (int nt = 0; nt < 4; ++nt) {
          bf16x8 vf0 = *(const bf16x8*)(&Vt[buf][(nt * 16 + lr) * 72 + lq * 8]);
          bf16x8 vf1 = *(const bf16x8*)(&Vt[buf][(nt * 16 + lr) * 72 + 32 + lq * 8]);
          o[nt] = mfma16(vf0, pf[0], o[nt]);
          o[nt] = mfma16(vf1, pf[1], o[nt]);
        }
      }

      if (jt + 1 < nkv) {
        stage(buf ^ 1);
        if (jt + 2 < nkv) load_tile(jt + 2);
        else if (phase == 0) load_tile(0);
        __syncthreads();
      }
    }

    {
      float inv = 1.f / li;
      int t_g = qmin + lr;
#pragma unroll
      for (int nt = 0; nt < 4; ++nt) {
        uint2 yv;
        yv.x = cvt_pk_bf16(o[nt][0] * inv, o[nt][1] * inv);
        yv.y = cvt_pk_bf16(o[nt][2] * inv, o[nt][3] * inv);
        *(uint2*)(Y + ((size_t)(b * T + t_g)) * 1024 + h * 64 + nt * 16 + lq * 4) = yv;
      }
    }
  }
}

// ---------------- launch ----------------
extern "C" void kernel_launch(void* const* d_in, const int* in_sizes, int n_in,
                              void* d_out, int out_size, void* d_ws, size_t ws_size,
                              hipStream_t stream) {
  const float* x = (const float*)d_in[0];       // [4,2048,1024]
  const float* qkv_w = (const float*)d_in[1];   // [3072,1024]
  const float* qkv_b = (const float*)d_in[2];   // [3072]
  const float* proj_w = (const float*)d_in[3];  // [1024,1024]
  const float* proj_b = (const float*)d_in[4];  // [1024]
  float* out = (float*)d_out;                   // [4,2048,1024] fp32

  unsigned short* ws = (unsigned short*)d_ws;
  unsigned short* xb = ws;                     // 8388608
  unsigned short* wqkv = xb + 8388608;         // 3145728
  unsigned short* wproj = wqkv + 3145728;      // 1048576
  unsigned short* Qb = wproj + 1048576;        // 8388608 [B,H,T,hd]
  unsigned short* Kb = Qb + 8388608;           // 8388608
  unsigned short* Vb = Kb + 8388608;           // 8388608
  unsigned short* Yb = Vb + 8388608;           // 8388608 [B*T, C]

  auto* g0 = gemm8<0>;
  auto* g1 = gemm8<1>;
  static bool attr_set = false;
  if (!attr_set) {
    (void)hipFuncSetAttribute((const void*)g0,
                              hipFuncAttributeMaxDynamicSharedMemorySize, 131072);
    (void)hipFuncSetAttribute((const void*)g1,
                              hipFuncAttributeMaxDynamicSharedMemorySize, 131072);
    attr_set = true;
  }

  cvt_kernel<<<8388608 / 1024, 256, 0, stream>>>(x, xb, 8388608);
  cvt_kernel<<<3145728 / 1024, 256, 0, stream>>>(qkv_w, wqkv, 3145728);
  cvt_kernel<<<1048576 / 1024, 256, 0, stream>>>(proj_w, wproj, 1048576);

  // QKV: M=8192, N=3072, K=1024 -> grid 12*32=384 (384%8==0)
  gemm8<0><<<dim3(384), 512, 131072, stream>>>(xb, wqkv, qkv_b, nullptr, Qb, Kb, Vb,
                                               8192, 3072, 1024, 12);
  attn_kernel<<<dim3(8, 16, 4), 512, 0, stream>>>(Qb, Kb, Vb, Yb);
  // proj: M=8192, N=1024, K=1024 -> grid 4*32=128 (128%8==0)
  gemm8<1><<<dim3(128), 512, 131072, stream>>>(Yb, wproj, proj_b, out, nullptr, nullptr,
                                               nullptr, 8192, 1024, 1024, 4);
}

// Round 3
// 257.608 us; speedup vs baseline: 1.1521x; 1.0146x over previous
//
#include <hip/hip_runtime.h>
#include <stdint.h>
#include <math.h>

#define DEVI __device__ __forceinline__

typedef __attribute__((ext_vector_type(8))) short bf16x8;
typedef __attribute__((ext_vector_type(4))) float f32x4;

DEVI unsigned short f2bf(float f) {
  union { float f; unsigned u; } v; v.f = f;
  unsigned u = v.u;
  u += 0x7fffu + ((u >> 16) & 1u);   // round-to-nearest-even
  return (unsigned short)(u >> 16);
}

// pack two f32 -> one dword of 2x bf16 (lo = a, hi = b), RNE; no builtin on gfx950
DEVI unsigned cvt_pk_bf16(float a, float b) {
  unsigned r;
  asm("v_cvt_pk_bf16_f32 %0, %1, %2" : "=v"(r) : "v"(a), "v"(b));
  return r;
}

DEVI f32x4 mfma16(bf16x8 a, bf16x8 b, f32x4 c) {
  return __builtin_amdgcn_mfma_f32_16x16x32_bf16(a, b, c, 0, 0, 0);
}

// async global->LDS, 16 B per lane; LDS dest = wave-uniform base + lane*16
DEVI void gld16(const unsigned short* g, unsigned short* l) {
  __builtin_amdgcn_global_load_lds(
      (const __attribute__((address_space(1))) unsigned int*)(uintptr_t)g,
      (__attribute__((address_space(3))) unsigned int*)(unsigned int)(uintptr_t)l,
      16, 0, 0);
}

#define VMCNT(n) asm volatile("s_waitcnt vmcnt(" #n ")" ::: "memory")
#define BAR()                              \
  do {                                     \
    __builtin_amdgcn_s_barrier();          \
    __builtin_amdgcn_sched_barrier(0);     \
  } while (0)

// ---------------- fp32 -> bf16 convert ----------------
__global__ __launch_bounds__(256) void cvt_kernel(const float* __restrict__ in,
                                                  unsigned short* __restrict__ out, int n) {
  int i = (blockIdx.x * 256 + threadIdx.x) * 4;
  if (i < n) {
    float4 v = *(const float4*)(in + i);
    unsigned lo = f2bf(v.x) | ((unsigned)f2bf(v.y) << 16);
    unsigned hi = f2bf(v.z) | ((unsigned)f2bf(v.w) << 16);
    uint2 o; o.x = lo; o.y = hi;
    *(uint2*)(out + i) = o;
  }
}

// ======== 256x256 deep-pipelined GEMM: C[M,N] = A[M,K]*Bw[N,K]^T + bias ========
// 512 threads = 8 waves (2M x 4N), wave tile 128x64, BK=64, LDS 128 KiB dbuf.
// Counted-vmcnt 8-phase-style schedule; see round-2 notes. MODE==0 writes
// Q,K as [b,h,t,d] (scalar) and V TRANSPOSED as [b,h,d,t] (packed uint2).
template <int MODE>
__global__ __launch_bounds__(512, 2) void gemm8(
    const unsigned short* __restrict__ A, const unsigned short* __restrict__ Bw,
    const float* __restrict__ bias, float* __restrict__ Cf,
    unsigned short* __restrict__ Qo, unsigned short* __restrict__ Ko,
    unsigned short* __restrict__ Vo, int M, int N, int K, int nbx) {
  extern __shared__ unsigned short lds[];   // [buf][As 16384 | Bs 16384] ushorts
  const int tid = threadIdx.x;
  const int lane = tid & 63;
  const int w = tid >> 6;                   // 0..7
  const int wm = w >> 2, wn = w & 3;
  const int lr = lane & 15, lq = lane >> 4;

  // T1: XCD-aware block swizzle (grid % 8 == 0 for both call sites)
  const int cpx = gridDim.x >> 3;
  const int swz = (blockIdx.x & 7) * cpx + (blockIdx.x >> 3);
  const int bx = swz % nbx, by = swz / nbx;
  const int m0 = by * 256, n0 = bx * 256;

  // staging source coords (swizzle baked into the per-lane global column)
  const int sr = lane >> 3;                       // 0..7 row within chunk
  const int sc = ((lane & 7) ^ sr) << 3;          // swizzled col element
  const unsigned short* pa = A + (size_t)(m0 + sr) * K + sc;
  const unsigned short* pb = Bw + (size_t)(n0 + sr) * K + sc;

  // per-wave chunk ids (chunk = 8 rows = 1 KiB) for each unit
  const int aA0 = w, aA1 = 16 + w;                       // A_a
  const int aB0 = 8 + w, aB1 = 24 + w;                   // A_b
  const int bA0 = (w & 3) + ((w >> 2) << 3), bA1 = bA0 + 16;  // B_a
  const int bB0 = bA0 + 4, bB1 = bA1 + 4;                // B_b

  // fragment-read block swizzle offsets (ushorts); row&7 == lr&7 for all frags
  const int bs0 = (lq ^ (lr & 7)) << 3;
  const int bs1 = ((lq + 4) ^ (lr & 7)) << 3;

  f32x4 acc[8][4] = {};

  auto sA = [&](int buf, int kt, int c) {
    gld16(pa + (size_t)(c << 3) * K + kt, lds + buf * 32768 + (c << 9));
  };
  auto sB = [&](int buf, int kt, int c) {
    gld16(pb + (size_t)(c << 3) * K + kt, lds + buf * 32768 + 16384 + (c << 9));
  };

#define PH(buf, mh, nh)                                                          \
  {                                                                              \
    const unsigned short* As_ = lds + (buf) * 32768;                             \
    const unsigned short* Bs_ = As_ + 16384;                                     \
    bf16x8 a0[4], a1[4], b0[2], b1[2];                                           \
    _Pragma("unroll") for (int i = 0; i < 4; ++i) {                              \
      int ar = wm * 128 + (mh) * 64 + i * 16 + lr;                               \
      a0[i] = *(const bf16x8*)(As_ + ar * 64 + bs0);                             \
      a1[i] = *(const bf16x8*)(As_ + ar * 64 + bs1);                             \
    }                                                                            \
    _Pragma("unroll") for (int j = 0; j < 2; ++j) {                              \
      int br = wn * 64 + (nh) * 32 + j * 16 + lr;                                \
      b0[j] = *(const bf16x8*)(Bs_ + br * 64 + bs0);                             \
      b1[j] = *(const bf16x8*)(Bs_ + br * 64 + bs1);                             \
    }                                                                            \
    __builtin_amdgcn_s_setprio(1);                                               \
    _Pragma("unroll") for (int i = 0; i < 4; ++i)                                \
      _Pragma("unroll") for (int j = 0; j < 2; ++j) {                            \
        acc[(mh) * 4 + i][(nh) * 2 + j] =                                        \
            mfma16(a0[i], b0[j], acc[(mh) * 4 + i][(nh) * 2 + j]);               \
        acc[(mh) * 4 + i][(nh) * 2 + j] =                                        \
            mfma16(a1[i], b1[j], acc[(mh) * 4 + i][(nh) * 2 + j]);               \
      }                                                                          \
    __builtin_amdgcn_s_setprio(0);                                               \
  }

  // prologue: tile 0 into buf0 (unit order A_a, B_a, B_b, A_b)
  sA(0, 0, aA0); sA(0, 0, aA1);
  sB(0, 0, bA0); sB(0, 0, bA1);
  sB(0, 0, bB0); sB(0, 0, bB1);
  sA(0, 0, aB0); sA(0, 0, aB1);
  VMCNT(4);      // A_a(0), B_a(0) landed
  BAR();

  const int NT = K >> 6;
  for (int t = 0; t < NT - 1; ++t) {
    const int buf = t & 1, nb = buf ^ 1;
    const int kt = (t + 1) << 6;
    sA(nb, kt, aA0); sA(nb, kt, aA1);
    PH(buf, 0, 0);
    VMCNT(4); BAR();                 // B_b(t) landed for all waves
    sB(nb, kt, bA0); sB(nb, kt, bA1);
    PH(buf, 0, 1);
    VMCNT(4); BAR();                 // A_b(t) landed for all waves
    sB(nb, kt, bB0); sB(nb, kt, bB1);
    PH(buf, 1, 0);
    sA(nb, kt, aB0); sA(nb, kt, aB1);
    PH(buf, 1, 1);
    VMCNT(4); BAR();                 // A_a(t+1), B_a(t+1) landed
  }
  { // peeled last tile
    const int buf = (NT - 1) & 1;
    PH(buf, 0, 0);
    VMCNT(2); BAR();
    PH(buf, 0, 1);
    VMCNT(0); BAR();
    PH(buf, 1, 0);
    PH(buf, 1, 1);
  }
#undef PH

  // epilogue (wave tile 128x64)
#pragma unroll
  for (int mt = 0; mt < 8; ++mt) {
#pragma unroll
    for (int nt = 0; nt < 4; ++nt) {
      int n_g = n0 + wn * 64 + nt * 16 + lr;
      float bv = bias[n_g];
      if (MODE == 1) {
#pragma unroll
        for (int r = 0; r < 4; ++r) {
          int m_g = m0 + wm * 128 + mt * 16 + lq * 4 + r;
          Cf[(size_t)m_g * N + n_g] = acc[mt][nt][r] + bv;
        }
      } else {
        int which = n_g >> 10;               // 0:Q 1:K 2:V (wave-uniform)
        int rem = n_g & 1023;
        int h = rem >> 6, d = rem & 63;
        int m_base = m0 + wm * 128 + mt * 16 + lq * 4;
        int b = m_base >> 11, tt = m_base & 2047;
        if (which == 2) {
          // V^T layout [b,h,d,t]; 4 consecutive t -> one uint2
          uint2 pv;
          pv.x = cvt_pk_bf16(acc[mt][nt][0] + bv, acc[mt][nt][1] + bv);
          pv.y = cvt_pk_bf16(acc[mt][nt][2] + bv, acc[mt][nt][3] + bv);
          *(uint2*)(Vo + (((size_t)(b * 16 + h) * 64 + d) * 2048 + tt)) = pv;
        } else {
          unsigned short* p = (which == 0) ? Qo : Ko;
#pragma unroll
          for (int r = 0; r < 4; ++r) {
            size_t idx = (((size_t)(b * 16 + h) * 2048) + tt + r) * 64 + d;
            p[idx] = f2bf(acc[mt][nt][r] + bv);
          }
        }
      }
    }
  }
}

// ------- flash attention (causal), S^T formulation, 128-row Q-tiles -------
// 8 waves x 16 q-rows; paired q-tiles (pair, 15-pair); dbuf K/V, one barrier/tile.
// V arrives TRANSPOSED [b,h,d,t] -> V staging is a single float4 LDS write.
// Softmax: scale folded into exp2-fma; T13 defer-max (THR=8); per-lane li.
__global__ __launch_bounds__(512, 4) void attn_kernel(
    const unsigned short* __restrict__ Q, const unsigned short* __restrict__ K,
    const unsigned short* __restrict__ V, unsigned short* __restrict__ Y) {
  constexpr int T = 2048, HD = 64, H = 16;
  __shared__ unsigned short Kt[2][64 * 72];   // K rows [kv][d], pad 8
  __shared__ unsigned short Vt[2][64 * 72];   // V^T    [d][kv], pad 8
  __shared__ unsigned short Pt[8][16 * 72];   // per-wave P, [q][kv]

  const int tid = threadIdx.x;
  const int lane = tid & 63;
  const int w = tid >> 6;                     // 0..7
  const int lr = lane & 15, lq = lane >> 4;
  const int pair = blockIdx.x;                // 0..7
  const int h = blockIdx.y;
  const int b = blockIdx.z;
  const size_t bh = (size_t)(b * H + h) * T * HD;   // also V^T base (64*2048)
  const float SC = 0.125f * 1.44269504089f;   // 1/sqrt(64) * log2(e)

  const int krow = tid >> 3, kcb = (tid & 7) << 3;  // 64 rows x 64 cols tile

  float4 kr, vr;
  auto load_tile = [&](int jt) {
    const int c0 = jt * 64;
    kr = *(const float4*)(K + bh + (size_t)(c0 + krow) * HD + kcb);
    vr = *(const float4*)(V + bh + (size_t)krow * T + c0 + kcb);  // V^T row=d
  };
  auto stage = [&](int buf) {
    *(float4*)(&Kt[buf][krow * 72 + kcb]) = kr;
    *(float4*)(&Vt[buf][krow * 72 + kcb]) = vr;
  };

  load_tile(0);

  for (int phase = 0; phase < 2; ++phase) {
    const int qt = phase ? (15 - pair) : pair;
    const int q0 = qt * 128;
    const int nkv = 2 * qt + 2;
    const int qmin = q0 + w * 16;
    const int qmax = qmin + 15;

    bf16x8 qf[2];
#pragma unroll
    for (int kb = 0; kb < 2; ++kb)
      qf[kb] = *(const bf16x8*)(Q + bh + (size_t)(qmin + lr) * HD + kb * 32 + lq * 8);

    f32x4 o[4] = {};
    float mi = -INFINITY, li = 0.f;

    stage(0);
    load_tile(1);
    __syncthreads();

    for (int jt = 0; jt < nkv; ++jt) {
      const int c0 = jt * 64;
      const int buf = jt & 1;

      if (c0 <= qmax) {
        // S^T = K Q^T : rows kv, cols q
        f32x4 s[4];
        __builtin_amdgcn_s_setprio(1);
#pragma unroll
        for (int nt = 0; nt < 4; ++nt) {
          bf16x8 kf0 = *(const bf16x8*)(&Kt[buf][(nt * 16 + lr) * 72 + lq * 8]);
          bf16x8 kf1 = *(const bf16x8*)(&Kt[buf][(nt * 16 + lr) * 72 + 32 + lq * 8]);
          f32x4 z = {};
          z = mfma16(kf0, qf[0], z);
          s[nt] = mfma16(kf1, qf[1], z);
        }
        __builtin_amdgcn_s_setprio(0);
        // causal mask (raw domain), diagonal tiles only; scale folded into exp
        if (c0 + 63 > qmin) {
          int qg = qmin + lr;
#pragma unroll
          for (int nt = 0; nt < 4; ++nt)
#pragma unroll
            for (int r = 0; r < 4; ++r) {
              int kvg = c0 + nt * 16 + lq * 4 + r;
              if (kvg > qg) s[nt][r] = -INFINITY;
            }
        }
        // online softmax; row max in raw domain, compare in scaled domain
        float mx = -INFINITY;
#pragma unroll
        for (int nt = 0; nt < 4; ++nt)
          mx = fmaxf(mx, fmaxf(fmaxf(s[nt][0], s[nt][1]),
                               fmaxf(s[nt][2], s[nt][3])));
        mx = fmaxf(mx, __shfl_xor(mx, 16));
        mx = fmaxf(mx, __shfl_xor(mx, 32));
        float mxs = mx * SC;
        if (!__all(mxs <= mi + 8.f)) {       // T13 defer-max (THR=8)
          float mnew = fmaxf(mi, mxs);
          float alpha = __builtin_amdgcn_exp2f(mi - mnew);
          mi = mnew;
          li *= alpha;
#pragma unroll
          for (int nt = 0; nt < 4; ++nt)
#pragma unroll
            for (int r = 0; r < 4; ++r) o[nt][r] *= alpha;
        }
        float rs = 0.f;
#pragma unroll
        for (int nt = 0; nt < 4; ++nt) {
          float p0 = __builtin_amdgcn_exp2f(fmaf(s[nt][0], SC, -mi));
          float p1 = __builtin_amdgcn_exp2f(fmaf(s[nt][1], SC, -mi));
          float p2 = __builtin_amdgcn_exp2f(fmaf(s[nt][2], SC, -mi));
          float p3 = __builtin_amdgcn_exp2f(fmaf(s[nt][3], SC, -mi));
          rs += (p0 + p1) + (p2 + p3);
          uint2 pk;
          pk.x = cvt_pk_bf16(p0, p1);
          pk.y = cvt_pk_bf16(p2, p3);
          *(uint2*)(&Pt[w][lr * 72 + nt * 16 + lq * 4]) = pk;
        }
        li += rs;                            // per-lane partial; reduced at end
        // O^T += V^T P^T  (A = V^T frag, B = P^T frag)
        bf16x8 pf[2];
#pragma unroll
        for (int kb = 0; kb < 2; ++kb)
          pf[kb] = *(const bf16x8*)(&Pt[w][lr * 72 + kb * 32 + lq * 8]);
        __builtin_amdgcn_s_setprio(1);
#pragma unroll
        for (int nt = 0; nt < 4; ++nt) {
          bf16x8 vf0 = *(const bf16x8*)(&Vt[buf][(nt * 16 + lr) * 72 + lq * 8]);
          bf16x8 vf1 = *(const bf16x8*)(&Vt[buf][(nt * 16 + lr) * 72 + 32 + lq * 8]);
          o[nt] = mfma16(vf0, pf[0], o[nt]);
          o[nt] = mfma16(vf1, pf[1], o[nt]);
        }
        __builtin_amdgcn_s_setprio(0);
      }

      if (jt + 1 < nkv) {
        stage(buf ^ 1);
        if (jt + 2 < nkv) load_tile(jt + 2);
        else if (phase == 0) load_tile(0);
        __syncthreads();
      }
    }

    // epilogue: reduce per-lane li over the lr-quad, then write Y
    {
      li += __shfl_xor(li, 16);
      li += __shfl_xor(li, 32);
      float inv = 1.f / li;
      int t_g = qmin + lr;
#pragma unroll
      for (int nt = 0; nt < 4; ++nt) {
        uint2 yv;
        yv.x = cvt_pk_bf16(o[nt][0] * inv, o[nt][1] * inv);
        yv.y = cvt_pk_bf16(o[nt][2] * inv, o[nt][3] * inv);
        *(uint2*)(Y + ((size_t)(b * T + t_g)) * 1024 + h * 64 + nt * 16 + lq * 4) = yv;
      }
    }
  }
}

// ---------------- launch ----------------
extern "C" void kernel_launch(void* const* d_in, const int* in_sizes, int n_in,
                              void* d_out, int out_size, void* d_ws, size_t ws_size,
                              hipStream_t stream) {
  const float* x = (const float*)d_in[0];       // [4,2048,1024]
  const float* qkv_w = (const float*)d_in[1];   // [3072,1024]
  const float* qkv_b = (const float*)d_in[2];   // [3072]
  const float* proj_w = (const float*)d_in[3];  // [1024,1024]
  const float* proj_b = (const float*)d_in[4];  // [1024]
  float* out = (float*)d_out;                   // [4,2048,1024] fp32

  unsigned short* ws = (unsigned short*)d_ws;
  unsigned short* xb = ws;                     // 8388608
  unsigned short* wqkv = xb + 8388608;         // 3145728
  unsigned short* wproj = wqkv + 3145728;      // 1048576
  unsigned short* Qb = wproj + 1048576;        // 8388608 [B,H,T,hd]
  unsigned short* Kb = Qb + 8388608;           // 8388608 [B,H,T,hd]
  unsigned short* Vb = Kb + 8388608;           // 8388608 [B,H,hd,T] (transposed!)
  unsigned short* Yb = Vb + 8388608;           // 8388608 [B*T, C]

  auto* g0 = gemm8<0>;
  auto* g1 = gemm8<1>;
  static bool attr_set = false;
  if (!attr_set) {
    (void)hipFuncSetAttribute((const void*)g0,
                              hipFuncAttributeMaxDynamicSharedMemorySize, 131072);
    (void)hipFuncSetAttribute((const void*)g1,
                              hipFuncAttributeMaxDynamicSharedMemorySize, 131072);
    attr_set = true;
  }

  cvt_kernel<<<8388608 / 1024, 256, 0, stream>>>(x, xb, 8388608);
  cvt_kernel<<<3145728 / 1024, 256, 0, stream>>>(qkv_w, wqkv, 3145728);
  cvt_kernel<<<1048576 / 1024, 256, 0, stream>>>(proj_w, wproj, 1048576);

  // QKV: M=8192, N=3072, K=1024 -> grid 12*32=384 (384%8==0)
  gemm8<0><<<dim3(384), 512, 131072, stream>>>(xb, wqkv, qkv_b, nullptr, Qb, Kb, Vb,
                                               8192, 3072, 1024, 12);
  attn_kernel<<<dim3(8, 16, 4), 512, 0, stream>>>(Qb, Kb, Vb, Yb);
  // proj: M=8192, N=1024, K=1024 -> grid 4*32=128 (128%8==0)
  gemm8<1><<<dim3(128), 512, 131072, stream>>>(Yb, wproj, proj_b, out, nullptr, nullptr,
                                               nullptr, 8192, 1024, 1024, 4);
}

// Round 5
// 256.606 us; speedup vs baseline: 1.1566x; 1.0039x over previous
//
#include <hip/hip_runtime.h>
#include <stdint.h>
#include <math.h>

#define DEVI __device__ __forceinline__

typedef __attribute__((ext_vector_type(8))) short bf16x8;
typedef __attribute__((ext_vector_type(4))) float f32x4;

DEVI unsigned short f2bf(float f) {
  union { float f; unsigned u; } v; v.f = f;
  unsigned u = v.u;
  u += 0x7fffu + ((u >> 16) & 1u);   // round-to-nearest-even
  return (unsigned short)(u >> 16);
}

// pack two f32 -> one dword of 2x bf16 (lo = a, hi = b), RNE; no builtin on gfx950
DEVI unsigned cvt_pk_bf16(float a, float b) {
  unsigned r;
  asm("v_cvt_pk_bf16_f32 %0, %1, %2" : "=v"(r) : "v"(a), "v"(b));
  return r;
}

DEVI f32x4 mfma16(bf16x8 a, bf16x8 b, f32x4 c) {
  return __builtin_amdgcn_mfma_f32_16x16x32_bf16(a, b, c, 0, 0, 0);
}

// async global->LDS, 16 B per lane; LDS dest = wave-uniform base + lane*16
DEVI void gld16(const unsigned short* g, unsigned short* l) {
  __builtin_amdgcn_global_load_lds(
      (const __attribute__((address_space(1))) unsigned int*)(uintptr_t)g,
      (__attribute__((address_space(3))) unsigned int*)(unsigned int)(uintptr_t)l,
      16, 0, 0);
}

#define VMCNT(n) asm volatile("s_waitcnt vmcnt(" #n ")" ::: "memory")
#define BAR()                              \
  do {                                     \
    __builtin_amdgcn_s_barrier();          \
    __builtin_amdgcn_sched_barrier(0);     \
  } while (0)

// ---------------- fp32 -> bf16 convert (3 buffers, one launch) ----------------
__global__ __launch_bounds__(256) void cvt3_kernel(
    const float* __restrict__ a, unsigned short* __restrict__ oa,
    const float* __restrict__ b, unsigned short* __restrict__ ob,
    const float* __restrict__ c, unsigned short* __restrict__ oc) {
  int bid = blockIdx.x;
  const float* in; unsigned short* out; int i;
  if (bid < 8192)       { in = a; out = oa; i = bid; }
  else if (bid < 11264) { in = b; out = ob; i = bid - 8192; }
  else                  { in = c; out = oc; i = bid - 11264; }
  int idx = (i * 256 + (int)threadIdx.x) * 4;
  float4 v = *(const float4*)(in + idx);
  unsigned lo = f2bf(v.x) | ((unsigned)f2bf(v.y) << 16);
  unsigned hi = f2bf(v.z) | ((unsigned)f2bf(v.w) << 16);
  uint2 o; o.x = lo; o.y = hi;
  *(uint2*)(out + idx) = o;
}

// ======== 256x256 deep-pipelined GEMM: C[M,N] = A[M,K]*Bw[N,K]^T + bias ========
// (unchanged from round 3 — see notes there). MODE==0 writes Q,K as [b,h,t,d]
// and V TRANSPOSED as [b,h,d,t] (packed uint2).
template <int MODE>
__global__ __launch_bounds__(512, 2) void gemm8(
    const unsigned short* __restrict__ A, const unsigned short* __restrict__ Bw,
    const float* __restrict__ bias, float* __restrict__ Cf,
    unsigned short* __restrict__ Qo, unsigned short* __restrict__ Ko,
    unsigned short* __restrict__ Vo, int M, int N, int K, int nbx) {
  extern __shared__ unsigned short lds[];   // [buf][As 16384 | Bs 16384] ushorts
  const int tid = threadIdx.x;
  const int lane = tid & 63;
  const int w = tid >> 6;                   // 0..7
  const int wm = w >> 2, wn = w & 3;
  const int lr = lane & 15, lq = lane >> 4;

  const int cpx = gridDim.x >> 3;
  const int swz = (blockIdx.x & 7) * cpx + (blockIdx.x >> 3);
  const int bx = swz % nbx, by = swz / nbx;
  const int m0 = by * 256, n0 = bx * 256;

  const int sr = lane >> 3;                       // 0..7 row within chunk
  const int sc = ((lane & 7) ^ sr) << 3;          // swizzled col element
  const unsigned short* pa = A + (size_t)(m0 + sr) * K + sc;
  const unsigned short* pb = Bw + (size_t)(n0 + sr) * K + sc;

  const int aA0 = w, aA1 = 16 + w;                       // A_a
  const int aB0 = 8 + w, aB1 = 24 + w;                   // A_b
  const int bA0 = (w & 3) + ((w >> 2) << 3), bA1 = bA0 + 16;  // B_a
  const int bB0 = bA0 + 4, bB1 = bA1 + 4;                // B_b

  const int bs0 = (lq ^ (lr & 7)) << 3;
  const int bs1 = ((lq + 4) ^ (lr & 7)) << 3;

  f32x4 acc[8][4] = {};

  auto sA = [&](int buf, int kt, int c) {
    gld16(pa + (size_t)(c << 3) * K + kt, lds + buf * 32768 + (c << 9));
  };
  auto sB = [&](int buf, int kt, int c) {
    gld16(pb + (size_t)(c << 3) * K + kt, lds + buf * 32768 + 16384 + (c << 9));
  };

#define PH(buf, mh, nh)                                                          \
  {                                                                              \
    const unsigned short* As_ = lds + (buf) * 32768;                             \
    const unsigned short* Bs_ = As_ + 16384;                                     \
    bf16x8 a0[4], a1[4], b0[2], b1[2];                                           \
    _Pragma("unroll") for (int i = 0; i < 4; ++i) {                              \
      int ar = wm * 128 + (mh) * 64 + i * 16 + lr;                               \
      a0[i] = *(const bf16x8*)(As_ + ar * 64 + bs0);                             \
      a1[i] = *(const bf16x8*)(As_ + ar * 64 + bs1);                             \
    }                                                                            \
    _Pragma("unroll") for (int j = 0; j < 2; ++j) {                              \
      int br = wn * 64 + (nh) * 32 + j * 16 + lr;                                \
      b0[j] = *(const bf16x8*)(Bs_ + br * 64 + bs0);                             \
      b1[j] = *(const bf16x8*)(Bs_ + br * 64 + bs1);                             \
    }                                                                            \
    __builtin_amdgcn_s_setprio(1);                                               \
    _Pragma("unroll") for (int i = 0; i < 4; ++i)                                \
      _Pragma("unroll") for (int j = 0; j < 2; ++j) {                            \
        acc[(mh) * 4 + i][(nh) * 2 + j] =                                        \
            mfma16(a0[i], b0[j], acc[(mh) * 4 + i][(nh) * 2 + j]);               \
        acc[(mh) * 4 + i][(nh) * 2 + j] =                                        \
            mfma16(a1[i], b1[j], acc[(mh) * 4 + i][(nh) * 2 + j]);               \
      }                                                                          \
    __builtin_amdgcn_s_setprio(0);                                               \
  }

  sA(0, 0, aA0); sA(0, 0, aA1);
  sB(0, 0, bA0); sB(0, 0, bA1);
  sB(0, 0, bB0); sB(0, 0, bB1);
  sA(0, 0, aB0); sA(0, 0, aB1);
  VMCNT(4);
  BAR();

  const int NT = K >> 6;
  for (int t = 0; t < NT - 1; ++t) {
    const int buf = t & 1, nb = buf ^ 1;
    const int kt = (t + 1) << 6;
    sA(nb, kt, aA0); sA(nb, kt, aA1);
    PH(buf, 0, 0);
    VMCNT(4); BAR();
    sB(nb, kt, bA0); sB(nb, kt, bA1);
    PH(buf, 0, 1);
    VMCNT(4); BAR();
    sB(nb, kt, bB0); sB(nb, kt, bB1);
    PH(buf, 1, 0);
    sA(nb, kt, aB0); sA(nb, kt, aB1);
    PH(buf, 1, 1);
    VMCNT(4); BAR();
  }
  {
    const int buf = (NT - 1) & 1;
    PH(buf, 0, 0);
    VMCNT(2); BAR();
    PH(buf, 0, 1);
    VMCNT(0); BAR();
    PH(buf, 1, 0);
    PH(buf, 1, 1);
  }
#undef PH

#pragma unroll
  for (int mt = 0; mt < 8; ++mt) {
#pragma unroll
    for (int nt = 0; nt < 4; ++nt) {
      int n_g = n0 + wn * 64 + nt * 16 + lr;
      float bv = bias[n_g];
      if (MODE == 1) {
#pragma unroll
        for (int r = 0; r < 4; ++r) {
          int m_g = m0 + wm * 128 + mt * 16 + lq * 4 + r;
          Cf[(size_t)m_g * N + n_g] = acc[mt][nt][r] + bv;
        }
      } else {
        int which = n_g >> 10;               // 0:Q 1:K 2:V (wave-uniform)
        int rem = n_g & 1023;
        int h = rem >> 6, d = rem & 63;
        int m_base = m0 + wm * 128 + mt * 16 + lq * 4;
        int b = m_base >> 11, tt = m_base & 2047;
        if (which == 2) {
          uint2 pv;
          pv.x = cvt_pk_bf16(acc[mt][nt][0] + bv, acc[mt][nt][1] + bv);
          pv.y = cvt_pk_bf16(acc[mt][nt][2] + bv, acc[mt][nt][3] + bv);
          *(uint2*)(Vo + (((size_t)(b * 16 + h) * 64 + d) * 2048 + tt)) = pv;
        } else {
          unsigned short* p = (which == 0) ? Qo : Ko;
#pragma unroll
          for (int r = 0; r < 4; ++r) {
            size_t idx = (((size_t)(b * 16 + h) * 2048) + tt + r) * 64 + d;
            p[idx] = f2bf(acc[mt][nt][r] + bv);
          }
        }
      }
    }
  }
}

// ------- flash attention (causal), S^T formulation, 256-row Q-tiles -------
// 8 waves x 32 q-rows = 256 q-rows/block; paired q-tiles (pair, 7-pair) ->
// uniform 36 KV-iterations. Grid 256 blocks x 512 thr (1 block/CU).
// attn is LDS-BW-bound: 32 q-rows/wave halves K/V LDS reads per unit work.
// P path: per-wave 16-row Pt LDS round-trip (round-3-verified mapping),
// reused sequentially for qs=0,1 (compiler orders the WAR hazard in-wave);
// V fragments read once per tile for both qs. V arrives transposed [b,h,d,t].
__global__ __launch_bounds__(512, 2) void attn_kernel(
    const unsigned short* __restrict__ Q, const unsigned short* __restrict__ K,
    const unsigned short* __restrict__ V, unsigned short* __restrict__ Y) {
  constexpr int T = 2048, HD = 64, H = 16;
  __shared__ unsigned short Kt[2][64 * 72];   // K rows [kv][d], pad 8
  __shared__ unsigned short Vt[2][64 * 72];   // V^T    [d][kv], pad 8
  __shared__ unsigned short Pt[8][16 * 72];   // per-wave P, [q][kv]

  const int tid = threadIdx.x;
  const int lane = tid & 63;
  const int w = tid >> 6;                     // 0..7
  const int lr = lane & 15, lq = lane >> 4;
  const int pair = blockIdx.x;                // 0..3
  const int h = blockIdx.y;
  const int b = blockIdx.z;
  const size_t bh = (size_t)(b * H + h) * T * HD;   // also V^T base (64*2048)
  const float SC = 0.125f * 1.44269504089f;   // 1/sqrt(64) * log2(e)

  const int krow = tid >> 3, kcb = (tid & 7) << 3;  // 64 rows x 64 cols tile

  float4 kr, vr;
  auto load_tile = [&](int jt) {
    const int c0 = jt * 64;
    kr = *(const float4*)(K + bh + (size_t)(c0 + krow) * HD + kcb);
    vr = *(const float4*)(V + bh + (size_t)krow * T + c0 + kcb);  // V^T row=d
  };
  auto stage = [&](int buf) {
    *(float4*)(&Kt[buf][krow * 72 + kcb]) = kr;
    *(float4*)(&Vt[buf][krow * 72 + kcb]) = vr;
  };

  load_tile(0);

  for (int phase = 0; phase < 2; ++phase) {
    const int qt = phase ? (7 - pair) : pair;
    const int q0 = qt * 256;
    const int nkv = 4 * (qt + 1);
    const int qw = q0 + w * 32;          // wave's first q-row

    bf16x8 qf[2][2];
#pragma unroll
    for (int qs = 0; qs < 2; ++qs)
#pragma unroll
      for (int kb = 0; kb < 2; ++kb)
        qf[qs][kb] = *(const bf16x8*)(Q + bh + (size_t)(qw + qs * 16 + lr) * HD +
                                      kb * 32 + lq * 8);

    f32x4 o[2][4] = {};
    float mi[2] = {-INFINITY, -INFINITY}, li[2] = {0.f, 0.f};

    stage(0);
    load_tile(1);
    __syncthreads();

    for (int jt = 0; jt < nkv; ++jt) {
      const int c0 = jt * 64;
      const int buf = jt & 1;

      if (c0 <= qw + 31) {               // wave-uniform: else tile fully masked
        // S^T = K Q^T : rows kv, cols q (K frags shared across qs)
        f32x4 s[2][4];
        __builtin_amdgcn_s_setprio(1);
#pragma unroll
        for (int nt = 0; nt < 4; ++nt) {
          bf16x8 kf0 = *(const bf16x8*)(&Kt[buf][(nt * 16 + lr) * 72 + lq * 8]);
          bf16x8 kf1 = *(const bf16x8*)(&Kt[buf][(nt * 16 + lr) * 72 + 32 + lq * 8]);
#pragma unroll
          for (int qs = 0; qs < 2; ++qs) {
            f32x4 z = {};
            z = mfma16(kf0, qf[qs][0], z);
            s[qs][nt] = mfma16(kf1, qf[qs][1], z);
          }
        }
        __builtin_amdgcn_s_setprio(0);
        // causal mask (raw domain), diagonal-adjacent tiles only
        if (c0 + 63 > qw) {
#pragma unroll
          for (int qs = 0; qs < 2; ++qs) {
            int qg = qw + qs * 16 + lr;
#pragma unroll
            for (int nt = 0; nt < 4; ++nt)
#pragma unroll
              for (int r = 0; r < 4; ++r) {
                int kvg = c0 + nt * 16 + lq * 4 + r;
                if (kvg > qg) s[qs][nt][r] = -INFINITY;
              }
          }
        }
        // online softmax (scaled domain), T13 defer-max THR=8
        float mxs[2];
#pragma unroll
        for (int qs = 0; qs < 2; ++qs) {
          float mx = -INFINITY;
#pragma unroll
          for (int nt = 0; nt < 4; ++nt)
            mx = fmaxf(mx, fmaxf(fmaxf(s[qs][nt][0], s[qs][nt][1]),
                                 fmaxf(s[qs][nt][2], s[qs][nt][3])));
          mx = fmaxf(mx, __shfl_xor(mx, 16));
          mx = fmaxf(mx, __shfl_xor(mx, 32));
          mxs[qs] = mx * SC;
        }
        if (!__all((mxs[0] <= mi[0] + 8.f) && (mxs[1] <= mi[1] + 8.f))) {
#pragma unroll
          for (int qs = 0; qs < 2; ++qs) {
            float mnew = fmaxf(mi[qs], mxs[qs]);
            float alpha = __builtin_amdgcn_exp2f(mi[qs] - mnew);
            mi[qs] = mnew;
            li[qs] *= alpha;
#pragma unroll
            for (int nt = 0; nt < 4; ++nt)
#pragma unroll
              for (int r = 0; r < 4; ++r) o[qs][nt][r] *= alpha;
          }
        }
        // P = exp2(s*SC - mi) -> per-wave Pt -> B-frag regs (r3-verified path);
        // one 16-row Pt buffer reused across qs (in-wave LDS ordering).
        bf16x8 pf[2][2];
#pragma unroll
        for (int qs = 0; qs < 2; ++qs) {
          float rs = 0.f;
#pragma unroll
          for (int nt = 0; nt < 4; ++nt) {
            float p0 = __builtin_amdgcn_exp2f(fmaf(s[qs][nt][0], SC, -mi[qs]));
            float p1 = __builtin_amdgcn_exp2f(fmaf(s[qs][nt][1], SC, -mi[qs]));
            float p2 = __builtin_amdgcn_exp2f(fmaf(s[qs][nt][2], SC, -mi[qs]));
            float p3 = __builtin_amdgcn_exp2f(fmaf(s[qs][nt][3], SC, -mi[qs]));
            rs += (p0 + p1) + (p2 + p3);
            uint2 pk;
            pk.x = cvt_pk_bf16(p0, p1);
            pk.y = cvt_pk_bf16(p2, p3);
            *(uint2*)(&Pt[w][lr * 72 + nt * 16 + lq * 4]) = pk;
          }
          li[qs] += rs;                  // per-lane partial; reduced at end
#pragma unroll
          for (int kb = 0; kb < 2; ++kb)
            pf[qs][kb] = *(const bf16x8*)(&Pt[w][lr * 72 + kb * 32 + lq * 8]);
        }
        // O^T += V^T P^T (V frags read once, used for both qs)
        __builtin_amdgcn_s_setprio(1);
#pragma unroll
        for (int nt = 0; nt < 4; ++nt) {
          bf16x8 vf0 = *(const bf16x8*)(&Vt[buf][(nt * 16 + lr) * 72 + lq * 8]);
          bf16x8 vf1 = *(const bf16x8*)(&Vt[buf][(nt * 16 + lr) * 72 + 32 + lq * 8]);
#pragma unroll
          for (int qs = 0; qs < 2; ++qs) {
            o[qs][nt] = mfma16(vf0, pf[qs][0], o[qs][nt]);
            o[qs][nt] = mfma16(vf1, pf[qs][1], o[qs][nt]);
          }
        }
        __builtin_amdgcn_s_setprio(0);
      }

      if (jt + 1 < nkv) {
        stage(buf ^ 1);
        if (jt + 2 < nkv) load_tile(jt + 2);
        else if (phase == 0) load_tile(0);
        __syncthreads();
      }
    }

    // epilogue: reduce per-lane li over lq groups, write Y
#pragma unroll
    for (int qs = 0; qs < 2; ++qs) {
      float l = li[qs];
      l += __shfl_xor(l, 16);
      l += __shfl_xor(l, 32);
      float inv = 1.f / l;
      int t_g = qw + qs * 16 + lr;
#pragma unroll
      for (int nt = 0; nt < 4; ++nt) {
        uint2 yv;
        yv.x = cvt_pk_bf16(o[qs][nt][0] * inv, o[qs][nt][1] * inv);
        yv.y = cvt_pk_bf16(o[qs][nt][2] * inv, o[qs][nt][3] * inv);
        *(uint2*)(Y + ((size_t)(b * T + t_g)) * 1024 + h * 64 + nt * 16 + lq * 4) = yv;
      }
    }
  }
}

// ---------------- launch ----------------
extern "C" void kernel_launch(void* const* d_in, const int* in_sizes, int n_in,
                              void* d_out, int out_size, void* d_ws, size_t ws_size,
                              hipStream_t stream) {
  const float* x = (const float*)d_in[0];       // [4,2048,1024]
  const float* qkv_w = (const float*)d_in[1];   // [3072,1024]
  const float* qkv_b = (const float*)d_in[2];   // [3072]
  const float* proj_w = (const float*)d_in[3];  // [1024,1024]
  const float* proj_b = (const float*)d_in[4];  // [1024]
  float* out = (float*)d_out;                   // [4,2048,1024] fp32

  unsigned short* ws = (unsigned short*)d_ws;
  unsigned short* xb = ws;                     // 8388608
  unsigned short* wqkv = xb + 8388608;         // 3145728
  unsigned short* wproj = wqkv + 3145728;      // 1048576
  unsigned short* Qb = wproj + 1048576;        // 8388608 [B,H,T,hd]
  unsigned short* Kb = Qb + 8388608;           // 8388608 [B,H,T,hd]
  unsigned short* Vb = Kb + 8388608;           // 8388608 [B,H,hd,T] (transposed!)
  unsigned short* Yb = Vb + 8388608;           // 8388608 [B*T, C]

  auto* g0 = gemm8<0>;
  auto* g1 = gemm8<1>;
  static bool attr_set = false;
  if (!attr_set) {
    (void)hipFuncSetAttribute((const void*)g0,
                              hipFuncAttributeMaxDynamicSharedMemorySize, 131072);
    (void)hipFuncSetAttribute((const void*)g1,
                              hipFuncAttributeMaxDynamicSharedMemorySize, 131072);
    attr_set = true;
  }

  cvt3_kernel<<<12288, 256, 0, stream>>>(x, xb, qkv_w, wqkv, proj_w, wproj);

  // QKV: M=8192, N=3072, K=1024 -> grid 12*32=384 (384%8==0)
  gemm8<0><<<dim3(384), 512, 131072, stream>>>(xb, wqkv, qkv_b, nullptr, Qb, Kb, Vb,
                                               8192, 3072, 1024, 12);
  attn_kernel<<<dim3(4, 16, 4), 512, 0, stream>>>(Qb, Kb, Vb, Yb);
  // proj: M=8192, N=1024, K=1024 -> grid 4*32=128 (128%8==0)
  gemm8<1><<<dim3(128), 512, 131072, stream>>>(Yb, wproj, proj_b, out, nullptr, nullptr,
                                               nullptr, 8192, 1024, 1024, 4);
}

// Round 6
// 246.466 us; speedup vs baseline: 1.2041x; 1.0411x over previous
//
#include <hip/hip_runtime.h>
#include <stdint.h>
#include <math.h>

#define DEVI __device__ __forceinline__

typedef __attribute__((ext_vector_type(8))) short bf16x8;
typedef __attribute__((ext_vector_type(4))) float f32x4;

DEVI unsigned short f2bf(float f) {
  union { float f; unsigned u; } v; v.f = f;
  unsigned u = v.u;
  u += 0x7fffu + ((u >> 16) & 1u);   // round-to-nearest-even
  return (unsigned short)(u >> 16);
}

// pack two f32 -> one dword of 2x bf16 (lo = a, hi = b), RNE; no builtin on gfx950
DEVI unsigned cvt_pk_bf16(float a, float b) {
  unsigned r;
  asm("v_cvt_pk_bf16_f32 %0, %1, %2" : "=v"(r) : "v"(a), "v"(b));
  return r;
}

DEVI f32x4 mfma16(bf16x8 a, bf16x8 b, f32x4 c) {
  return __builtin_amdgcn_mfma_f32_16x16x32_bf16(a, b, c, 0, 0, 0);
}

// async global->LDS, 16 B per lane; LDS dest = wave-uniform base + lane*16
DEVI void gld16(const unsigned short* g, unsigned short* l) {
  __builtin_amdgcn_global_load_lds(
      (const __attribute__((address_space(1))) unsigned int*)(uintptr_t)g,
      (__attribute__((address_space(3))) unsigned int*)(unsigned int)(uintptr_t)l,
      16, 0, 0);
}

#define VMCNT(n) asm volatile("s_waitcnt vmcnt(" #n ")" ::: "memory")
#define BAR()                              \
  do {                                     \
    __builtin_amdgcn_s_barrier();          \
    __builtin_amdgcn_sched_barrier(0);     \
  } while (0)

// ---------------- fp32 -> bf16 convert (3 buffers, one launch) ----------------
__global__ __launch_bounds__(256) void cvt3_kernel(
    const float* __restrict__ a, unsigned short* __restrict__ oa,
    const float* __restrict__ b, unsigned short* __restrict__ ob,
    const float* __restrict__ c, unsigned short* __restrict__ oc) {
  int bid = blockIdx.x;
  const float* in; unsigned short* out; int i;
  if (bid < 8192)       { in = a; out = oa; i = bid; }
  else if (bid < 11264) { in = b; out = ob; i = bid - 8192; }
  else                  { in = c; out = oc; i = bid - 11264; }
  int idx = (i * 256 + (int)threadIdx.x) * 4;
  float4 v = *(const float4*)(in + idx);
  unsigned lo = f2bf(v.x) | ((unsigned)f2bf(v.y) << 16);
  unsigned hi = f2bf(v.z) | ((unsigned)f2bf(v.w) << 16);
  uint2 o; o.x = lo; o.y = hi;
  *(uint2*)(out + idx) = o;
}

// ======== 256x256 deep-pipelined GEMM: C[M,N] = A[M,K]*Bw[N,K]^T + bias ========
// 512 threads = 8 waves (2M x 4N), wave tile 128x64, BK=64, LDS 128 KiB dbuf.
// Round-6: fragment REUSE across quadrant phases (order (0,0),(0,1),(1,1),(1,0);
// A held per mh-half, both B halves held) -> 24 ds_read_b128/K-tile instead of
// 48. The kernel was ds_read-throughput-bound (4100 cy/K-tile vs 640 MFMA floor,
// 0 bank conflicts). Staging units / counted-vmcnt ledger unchanged from r2.
// MODE==0 writes Q,K as [b,h,t,d] and V TRANSPOSED as [b,h,d,t].
template <int MODE>
__global__ __launch_bounds__(512, 2) void gemm8(
    const unsigned short* __restrict__ A, const unsigned short* __restrict__ Bw,
    const float* __restrict__ bias, float* __restrict__ Cf,
    unsigned short* __restrict__ Qo, unsigned short* __restrict__ Ko,
    unsigned short* __restrict__ Vo, int M, int N, int K, int nbx) {
  extern __shared__ unsigned short lds[];   // [buf][As 16384 | Bs 16384] ushorts
  const int tid = threadIdx.x;
  const int lane = tid & 63;
  const int w = tid >> 6;                   // 0..7
  const int wm = w >> 2, wn = w & 3;
  const int lr = lane & 15, lq = lane >> 4;

  const int cpx = gridDim.x >> 3;
  const int swz = (blockIdx.x & 7) * cpx + (blockIdx.x >> 3);
  const int bx = swz % nbx, by = swz / nbx;
  const int m0 = by * 256, n0 = bx * 256;

  const int sr = lane >> 3;                       // 0..7 row within chunk
  const int sc = ((lane & 7) ^ sr) << 3;          // swizzled col element
  const unsigned short* pa = A + (size_t)(m0 + sr) * K + sc;
  const unsigned short* pb = Bw + (size_t)(n0 + sr) * K + sc;

  const int aA0 = w, aA1 = 16 + w;                       // A_a (rows 0-63,128-191)
  const int aB0 = 8 + w, aB1 = 24 + w;                   // A_b (rows 64-127,192-255)
  const int bA0 = (w & 3) + ((w >> 2) << 3), bA1 = bA0 + 16;  // B_a (cols x..x+31)
  const int bB0 = bA0 + 4, bB1 = bA1 + 4;                // B_b

  const int bs0 = (lq ^ (lr & 7)) << 3;
  const int bs1 = ((lq + 4) ^ (lr & 7)) << 3;

  f32x4 acc[8][4] = {};

  auto sA = [&](int buf, int kt, int c) {
    gld16(pa + (size_t)(c << 3) * K + kt, lds + buf * 32768 + (c << 9));
  };
  auto sB = [&](int buf, int kt, int c) {
    gld16(pb + (size_t)(c << 3) * K + kt, lds + buf * 32768 + 16384 + (c << 9));
  };

// load A fragments for mh-half: 4 frags x 2 k-halves (8 ds_read_b128)
#define LDA(A_, mh)                                                          \
  _Pragma("unroll") for (int i = 0; i < 4; ++i) {                            \
    int ar = wm * 128 + (mh) * 64 + i * 16 + lr;                             \
    A_[i][0] = *(const bf16x8*)(As_ + ar * 64 + bs0);                        \
    A_[i][1] = *(const bf16x8*)(As_ + ar * 64 + bs1);                        \
  }
// load B fragments for nh-half: 2 frags x 2 k-halves (4 ds_read_b128)
#define LDB(B_, nh)                                                          \
  _Pragma("unroll") for (int j = 0; j < 2; ++j) {                            \
    int br = wn * 64 + (nh) * 32 + j * 16 + lr;                              \
    B_[j][0] = *(const bf16x8*)(Bs_ + br * 64 + bs0);                        \
    B_[j][1] = *(const bf16x8*)(Bs_ + br * 64 + bs1);                        \
  }
// one C-quadrant x K=64: 16 MFMA from held fragments
#define MM(A_, B_, mh, nh)                                                   \
  __builtin_amdgcn_s_setprio(1);                                             \
  _Pragma("unroll") for (int i = 0; i < 4; ++i)                              \
    _Pragma("unroll") for (int j = 0; j < 2; ++j) {                          \
      acc[(mh) * 4 + i][(nh) * 2 + j] =                                      \
          mfma16(A_[i][0], B_[j][0], acc[(mh) * 4 + i][(nh) * 2 + j]);       \
      acc[(mh) * 4 + i][(nh) * 2 + j] =                                      \
          mfma16(A_[i][1], B_[j][1], acc[(mh) * 4 + i][(nh) * 2 + j]);       \
    }                                                                        \
  __builtin_amdgcn_s_setprio(0);

  // prologue: tile 0 into buf0 (unit order A_a, B_a, B_b, A_b)
  sA(0, 0, aA0); sA(0, 0, aA1);
  sB(0, 0, bA0); sB(0, 0, bA1);
  sB(0, 0, bB0); sB(0, 0, bB1);
  sA(0, 0, aB0); sA(0, 0, aB1);
  VMCNT(4);      // A_a(0), B_a(0) landed
  BAR();

  const int NT = K >> 6;
  for (int t = 0; t < NT - 1; ++t) {
    const int buf = t & 1, nb = buf ^ 1;
    const int kt = (t + 1) << 6;
    const unsigned short* As_ = lds + buf * 32768;
    const unsigned short* Bs_ = As_ + 16384;
    bf16x8 af[4][2], b0f[2][2], b1f[2][2];
    // phase 1: quadrant (0,0); stage A_a(t+1)
    sA(nb, kt, aA0); sA(nb, kt, aA1);
    LDA(af, 0); LDB(b0f, 0);
    MM(af, b0f, 0, 0);
    VMCNT(4); BAR();                 // B_b(t) landed for all waves
    // phase 2: (0,1); stage B_a(t+1); reuse A0
    sB(nb, kt, bA0); sB(nb, kt, bA1);
    LDB(b1f, 1);
    MM(af, b1f, 0, 1);
    VMCNT(4); BAR();                 // A_b(t) landed for all waves
    // phase 3: (1,1); stage B_b(t+1); reuse B1, load A1 (A0 dead)
    sB(nb, kt, bB0); sB(nb, kt, bB1);
    LDA(af, 1);
    MM(af, b1f, 1, 1);
    // phase 4: (1,0); stage A_b(t+1); reuse A1 and B0 — zero ds_reads
    sA(nb, kt, aB0); sA(nb, kt, aB1);
    MM(af, b0f, 1, 0);
    VMCNT(4); BAR();                 // A_a(t+1), B_a(t+1) landed
  }
  { // peeled last tile (no staging; same quadrant order, tighter gates)
    const int buf = (NT - 1) & 1;
    const unsigned short* As_ = lds + buf * 32768;
    const unsigned short* Bs_ = As_ + 16384;
    bf16x8 af[4][2], b0f[2][2], b1f[2][2];
    LDA(af, 0); LDB(b0f, 0);
    MM(af, b0f, 0, 0);
    VMCNT(2); BAR();                 // B_b(last) landed
    LDB(b1f, 1);
    MM(af, b1f, 0, 1);
    VMCNT(0); BAR();                 // A_b(last) landed
    LDA(af, 1);
    MM(af, b1f, 1, 1);
    MM(af, b0f, 1, 0);
  }
#undef LDA
#undef LDB
#undef MM

#pragma unroll
  for (int mt = 0; mt < 8; ++mt) {
#pragma unroll
    for (int nt = 0; nt < 4; ++nt) {
      int n_g = n0 + wn * 64 + nt * 16 + lr;
      float bv = bias[n_g];
      if (MODE == 1) {
#pragma unroll
        for (int r = 0; r < 4; ++r) {
          int m_g = m0 + wm * 128 + mt * 16 + lq * 4 + r;
          Cf[(size_t)m_g * N + n_g] = acc[mt][nt][r] + bv;
        }
      } else {
        int which = n_g >> 10;               // 0:Q 1:K 2:V (wave-uniform)
        int rem = n_g & 1023;
        int h = rem >> 6, d = rem & 63;
        int m_base = m0 + wm * 128 + mt * 16 + lq * 4;
        int b = m_base >> 11, tt = m_base & 2047;
        if (which == 2) {
          uint2 pv;
          pv.x = cvt_pk_bf16(acc[mt][nt][0] + bv, acc[mt][nt][1] + bv);
          pv.y = cvt_pk_bf16(acc[mt][nt][2] + bv, acc[mt][nt][3] + bv);
          *(uint2*)(Vo + (((size_t)(b * 16 + h) * 64 + d) * 2048 + tt)) = pv;
        } else {
          unsigned short* p = (which == 0) ? Qo : Ko;
#pragma unroll
          for (int r = 0; r < 4; ++r) {
            size_t idx = (((size_t)(b * 16 + h) * 2048) + tt + r) * 64 + d;
            p[idx] = f2bf(acc[mt][nt][r] + bv);
          }
        }
      }
    }
  }
}

// ------- flash attention (causal), S^T formulation, 256-row Q-tiles -------
// (unchanged from round 5 — see notes there)
__global__ __launch_bounds__(512, 2) void attn_kernel(
    const unsigned short* __restrict__ Q, const unsigned short* __restrict__ K,
    const unsigned short* __restrict__ V, unsigned short* __restrict__ Y) {
  constexpr int T = 2048, HD = 64, H = 16;
  __shared__ unsigned short Kt[2][64 * 72];   // K rows [kv][d], pad 8
  __shared__ unsigned short Vt[2][64 * 72];   // V^T    [d][kv], pad 8
  __shared__ unsigned short Pt[8][16 * 72];   // per-wave P, [q][kv]

  const int tid = threadIdx.x;
  const int lane = tid & 63;
  const int w = tid >> 6;                     // 0..7
  const int lr = lane & 15, lq = lane >> 4;
  const int pair = blockIdx.x;                // 0..3
  const int h = blockIdx.y;
  const int b = blockIdx.z;
  const size_t bh = (size_t)(b * H + h) * T * HD;   // also V^T base (64*2048)
  const float SC = 0.125f * 1.44269504089f;   // 1/sqrt(64) * log2(e)

  const int krow = tid >> 3, kcb = (tid & 7) << 3;  // 64 rows x 64 cols tile

  float4 kr, vr;
  auto load_tile = [&](int jt) {
    const int c0 = jt * 64;
    kr = *(const float4*)(K + bh + (size_t)(c0 + krow) * HD + kcb);
    vr = *(const float4*)(V + bh + (size_t)krow * T + c0 + kcb);  // V^T row=d
  };
  auto stage = [&](int buf) {
    *(float4*)(&Kt[buf][krow * 72 + kcb]) = kr;
    *(float4*)(&Vt[buf][krow * 72 + kcb]) = vr;
  };

  load_tile(0);

  for (int phase = 0; phase < 2; ++phase) {
    const int qt = phase ? (7 - pair) : pair;
    const int q0 = qt * 256;
    const int nkv = 4 * (qt + 1);
    const int qw = q0 + w * 32;          // wave's first q-row

    bf16x8 qf[2][2];
#pragma unroll
    for (int qs = 0; qs < 2; ++qs)
#pragma unroll
      for (int kb = 0; kb < 2; ++kb)
        qf[qs][kb] = *(const bf16x8*)(Q + bh + (size_t)(qw + qs * 16 + lr) * HD +
                                      kb * 32 + lq * 8);

    f32x4 o[2][4] = {};
    float mi[2] = {-INFINITY, -INFINITY}, li[2] = {0.f, 0.f};

    stage(0);
    load_tile(1);
    __syncthreads();

    for (int jt = 0; jt < nkv; ++jt) {
      const int c0 = jt * 64;
      const int buf = jt & 1;

      if (c0 <= qw + 31) {               // wave-uniform: else tile fully masked
        // S^T = K Q^T : rows kv, cols q (K frags shared across qs)
        f32x4 s[2][4];
        __builtin_amdgcn_s_setprio(1);
#pragma unroll
        for (int nt = 0; nt < 4; ++nt) {
          bf16x8 kf0 = *(const bf16x8*)(&Kt[buf][(nt * 16 + lr) * 72 + lq * 8]);
          bf16x8 kf1 = *(const bf16x8*)(&Kt[buf][(nt * 16 + lr) * 72 + 32 + lq * 8]);
#pragma unroll
          for (int qs = 0; qs < 2; ++qs) {
            f32x4 z = {};
            z = mfma16(kf0, qf[qs][0], z);
            s[qs][nt] = mfma16(kf1, qf[qs][1], z);
          }
        }
        __builtin_amdgcn_s_setprio(0);
        // causal mask (raw domain), diagonal-adjacent tiles only
        if (c0 + 63 > qw) {
#pragma unroll
          for (int qs = 0; qs < 2; ++qs) {
            int qg = qw + qs * 16 + lr;
#pragma unroll
            for (int nt = 0; nt < 4; ++nt)
#pragma unroll
              for (int r = 0; r < 4; ++r) {
                int kvg = c0 + nt * 16 + lq * 4 + r;
                if (kvg > qg) s[qs][nt][r] = -INFINITY;
              }
          }
        }
        // online softmax (scaled domain), T13 defer-max THR=8
        float mxs[2];
#pragma unroll
        for (int qs = 0; qs < 2; ++qs) {
          float mx = -INFINITY;
#pragma unroll
          for (int nt = 0; nt < 4; ++nt)
            mx = fmaxf(mx, fmaxf(fmaxf(s[qs][nt][0], s[qs][nt][1]),
                                 fmaxf(s[qs][nt][2], s[qs][nt][3])));
          mx = fmaxf(mx, __shfl_xor(mx, 16));
          mx = fmaxf(mx, __shfl_xor(mx, 32));
          mxs[qs] = mx * SC;
        }
        if (!__all((mxs[0] <= mi[0] + 8.f) && (mxs[1] <= mi[1] + 8.f))) {
#pragma unroll
          for (int qs = 0; qs < 2; ++qs) {
            float mnew = fmaxf(mi[qs], mxs[qs]);
            float alpha = __builtin_amdgcn_exp2f(mi[qs] - mnew);
            mi[qs] = mnew;
            li[qs] *= alpha;
#pragma unroll
            for (int nt = 0; nt < 4; ++nt)
#pragma unroll
              for (int r = 0; r < 4; ++r) o[qs][nt][r] *= alpha;
          }
        }
        // P = exp2(s*SC - mi) -> per-wave Pt -> B-frag regs (r3-verified path);
        // one 16-row Pt buffer reused across qs (in-wave LDS ordering).
        bf16x8 pf[2][2];
#pragma unroll
        for (int qs = 0; qs < 2; ++qs) {
          float rs = 0.f;
#pragma unroll
          for (int nt = 0; nt < 4; ++nt) {
            float p0 = __builtin_amdgcn_exp2f(fmaf(s[qs][nt][0], SC, -mi[qs]));
            float p1 = __builtin_amdgcn_exp2f(fmaf(s[qs][nt][1], SC, -mi[qs]));
            float p2 = __builtin_amdgcn_exp2f(fmaf(s[qs][nt][2], SC, -mi[qs]));
            float p3 = __builtin_amdgcn_exp2f(fmaf(s[qs][nt][3], SC, -mi[qs]));
            rs += (p0 + p1) + (p2 + p3);
            uint2 pk;
            pk.x = cvt_pk_bf16(p0, p1);
            pk.y = cvt_pk_bf16(p2, p3);
            *(uint2*)(&Pt[w][lr * 72 + nt * 16 + lq * 4]) = pk;
          }
          li[qs] += rs;                  // per-lane partial; reduced at end
#pragma unroll
          for (int kb = 0; kb < 2; ++kb)
            pf[qs][kb] = *(const bf16x8*)(&Pt[w][lr * 72 + kb * 32 + lq * 8]);
        }
        // O^T += V^T P^T (V frags read once, used for both qs)
        __builtin_amdgcn_s_setprio(1);
#pragma unroll
        for (int nt = 0; nt < 4; ++nt) {
          bf16x8 vf0 = *(const bf16x8*)(&Vt[buf][(nt * 16 + lr) * 72 + lq * 8]);
          bf16x8 vf1 = *(const bf16x8*)(&Vt[buf][(nt * 16 + lr) * 72 + 32 + lq * 8]);
#pragma unroll
          for (int qs = 0; qs < 2; ++qs) {
            o[qs][nt] = mfma16(vf0, pf[qs][0], o[qs][nt]);
            o[qs][nt] = mfma16(vf1, pf[qs][1], o[qs][nt]);
          }
        }
        __builtin_amdgcn_s_setprio(0);
      }

      if (jt + 1 < nkv) {
        stage(buf ^ 1);
        if (jt + 2 < nkv) load_tile(jt + 2);
        else if (phase == 0) load_tile(0);
        __syncthreads();
      }
    }

    // epilogue: reduce per-lane li over lq groups, write Y
#pragma unroll
    for (int qs = 0; qs < 2; ++qs) {
      float l = li[qs];
      l += __shfl_xor(l, 16);
      l += __shfl_xor(l, 32);
      float inv = 1.f / l;
      int t_g = qw + qs * 16 + lr;
#pragma unroll
      for (int nt = 0; nt < 4; ++nt) {
        uint2 yv;
        yv.x = cvt_pk_bf16(o[qs][nt][0] * inv, o[qs][nt][1] * inv);
        yv.y = cvt_pk_bf16(o[qs][nt][2] * inv, o[qs][nt][3] * inv);
        *(uint2*)(Y + ((size_t)(b * T + t_g)) * 1024 + h * 64 + nt * 16 + lq * 4) = yv;
      }
    }
  }
}

// ---------------- launch ----------------
extern "C" void kernel_launch(void* const* d_in, const int* in_sizes, int n_in,
                              void* d_out, int out_size, void* d_ws, size_t ws_size,
                              hipStream_t stream) {
  const float* x = (const float*)d_in[0];       // [4,2048,1024]
  const float* qkv_w = (const float*)d_in[1];   // [3072,1024]
  const float* qkv_b = (const float*)d_in[2];   // [3072]
  const float* proj_w = (const float*)d_in[3];  // [1024,1024]
  const float* proj_b = (const float*)d_in[4];  // [1024]
  float* out = (float*)d_out;                   // [4,2048,1024] fp32

  unsigned short* ws = (unsigned short*)d_ws;
  unsigned short* xb = ws;                     // 8388608
  unsigned short* wqkv = xb + 8388608;         // 3145728
  unsigned short* wproj = wqkv + 3145728;      // 1048576
  unsigned short* Qb = wproj + 1048576;        // 8388608 [B,H,T,hd]
  unsigned short* Kb = Qb + 8388608;           // 8388608 [B,H,T,hd]
  unsigned short* Vb = Kb + 8388608;           // 8388608 [B,H,hd,T] (transposed!)
  unsigned short* Yb = Vb + 8388608;           // 8388608 [B*T, C]

  auto* g0 = gemm8<0>;
  auto* g1 = gemm8<1>;
  static bool attr_set = false;
  if (!attr_set) {
    (void)hipFuncSetAttribute((const void*)g0,
                              hipFuncAttributeMaxDynamicSharedMemorySize, 131072);
    (void)hipFuncSetAttribute((const void*)g1,
                              hipFuncAttributeMaxDynamicSharedMemorySize, 131072);
    attr_set = true;
  }

  cvt3_kernel<<<12288, 256, 0, stream>>>(x, xb, qkv_w, wqkv, proj_w, wproj);

  // QKV: M=8192, N=3072, K=1024 -> grid 12*32=384 (384%8==0)
  gemm8<0><<<dim3(384), 512, 131072, stream>>>(xb, wqkv, qkv_b, nullptr, Qb, Kb, Vb,
                                               8192, 3072, 1024, 12);
  attn_kernel<<<dim3(4, 16, 4), 512, 0, stream>>>(Qb, Kb, Vb, Yb);
  // proj: M=8192, N=1024, K=1024 -> grid 4*32=128 (128%8==0)
  gemm8<1><<<dim3(128), 512, 131072, stream>>>(Yb, wproj, proj_b, out, nullptr, nullptr,
                                               nullptr, 8192, 1024, 1024, 4);
}